// Round 4
// baseline (513.871 us; speedup 1.0000x reference)
//
#include <hip/hip_runtime.h>

#define HID 10
#define TT  2048
#define BB  4096

__device__ __forceinline__ float fast_tanh(float x) {
    // tanh(x) = 1 - 2/(exp2(x*2*log2e) + 1); saturates correctly at +-inf
    float e = exp2f(x * 2.885390081777926814f);
    float r = __builtin_amdgcn_rcpf(e + 1.0f);
    return fmaf(-2.0f, r, 1.0f);
}

// DPP row-rotate within 16-lane rows; direction handled by self-calibration.
template<int CTRL>
__device__ __forceinline__ int rori(int v) {
    return __builtin_amdgcn_update_dpp(0, v, CTRL, 0xF, 0xF, true);
}
template<int CTRL>
__device__ __forceinline__ float rorf(float v) {
    return __int_as_float(
        __builtin_amdgcn_update_dpp(0, __float_as_int(v), CTRL, 0xF, 0xF, true));
}

#define ROT15(dst, src)                                      \
    dst[0]  = (src);                                         \
    dst[1]  = rorf<0x121>(src); dst[2]  = rorf<0x122>(src);  \
    dst[3]  = rorf<0x123>(src); dst[4]  = rorf<0x124>(src);  \
    dst[5]  = rorf<0x125>(src); dst[6]  = rorf<0x126>(src);  \
    dst[7]  = rorf<0x127>(src); dst[8]  = rorf<0x128>(src);  \
    dst[9]  = rorf<0x129>(src); dst[10] = rorf<0x12A>(src);  \
    dst[11] = rorf<0x12B>(src); dst[12] = rorf<0x12C>(src);  \
    dst[13] = rorf<0x12D>(src); dst[14] = rorf<0x12E>(src);  \
    dst[15] = rorf<0x12F>(src);

// lane = hidden-unit slot (10 active of 16), 4 rows/wave, 1024 waves.
// h0 broadcast: DPP rotations (VALU, ~6cyc) -- on the serial critical path.
//   One rotation set of h0(t) feeds BOTH layer1(t) and layer0(t+1).
// h1 broadcast: LDS write+read, consumed one full step later (latency-slack).
// out-dot: ror-butterfly all-reduce (no wout vector needed).
__global__ void __launch_bounds__(64) rnn_kernel(
    const float* __restrict__ x,    const float* __restrict__ hs,
    const float* __restrict__ Wih0, const float* __restrict__ Whh0,
    const float* __restrict__ bih0, const float* __restrict__ bhh0,
    const float* __restrict__ Wih1, const float* __restrict__ Whh1,
    const float* __restrict__ bih1, const float* __restrict__ bhh1,
    const float* __restrict__ Wout, const float* __restrict__ boutp,
    float* __restrict__ out)
{
    const int tid  = threadIdx.x;
    const int lane = tid & 15;          // hidden unit slot
    const int grp  = tid >> 4;          // row within wave
    const int row  = blockIdx.x * 4 + grp;

    // 48-float stride => group bases 16 banks apart => <=2-way aliasing (free)
    __shared__ float lds[4 * 48];
    float* hbuf = &lds[grp * 48];

    // self-calibrate rotation source lanes: jj[r] = unit delivered by ror_r
    int jj[16];
    jj[0]  = lane;
    jj[1]  = rori<0x121>(lane);  jj[2]  = rori<0x122>(lane);
    jj[3]  = rori<0x123>(lane);  jj[4]  = rori<0x124>(lane);
    jj[5]  = rori<0x125>(lane);  jj[6]  = rori<0x126>(lane);
    jj[7]  = rori<0x127>(lane);  jj[8]  = rori<0x128>(lane);
    jj[9]  = rori<0x129>(lane);  jj[10] = rori<0x12A>(lane);
    jj[11] = rori<0x12B>(lane);  jj[12] = rori<0x12C>(lane);
    jj[13] = rori<0x12D>(lane);  jj[14] = rori<0x12E>(lane);
    jj[15] = rori<0x12F>(lane);

    const bool act = (lane < HID);

    // rotation-indexed weight rows (zeros for dummy units / dummy sources)
    float whh0r[16], wih1r[16];
    #pragma unroll
    for (int r = 0; r < 16; ++r) {
        const int j = jj[r];
        const bool ok = act && (j < HID);
        whh0r[r] = ok ? Whh0[lane * HID + j] : 0.f;
        wih1r[r] = ok ? Wih1[lane * HID + j] : 0.f;
    }
    // unit-indexed Whh1 row (h1 arrives unit-ordered via LDS broadcast)
    float whh1[HID];
    #pragma unroll
    for (int j = 0; j < HID; ++j) whh1[j] = act ? Whh1[lane * HID + j] : 0.f;

    const float wih0i = act ? Wih0[lane] : 0.f;
    const float b0c   = act ? (bih0[lane] + bhh0[lane]) : 0.f;
    const float b1c   = act ? (bih1[lane] + bhh1[lane]) : 0.f;
    const float woutu = act ? Wout[lane] : 0.f;
    const float bo    = boutp[0];

    // lane-resident own-unit state
    float h0own = act ? hs[row * HID + lane] : 0.f;
    float h1own = act ? hs[BB * HID + row * HID + lane] : 0.f;

    // loop-carried: rotations of h0(t-1)
    float rot[16];
    ROT15(rot, h0own);

    // loop-carried: unit-ordered h1(t-1) broadcast (init direct from global)
    const float* h1i = hs + (size_t)BB * HID + (size_t)row * HID;
    float4 m0 = make_float4(h1i[0], h1i[1], h1i[2], h1i[3]);
    float4 m1 = make_float4(h1i[4], h1i[5], h1i[6], h1i[7]);
    float2 m2 = make_float2(h1i[8], h1i[9]);

    const float* xrow = x   + (size_t)row * TT;
    float*       orow = out + (size_t)row * TT;

    float4 xcur = *(const float4*)(xrow);
    float st0, st1, st2, st3;

    for (int b = 0; b < TT / 4; ++b) {
        const int pf = (b + 1 < TT / 4) ? (b + 1) * 4 : (TT / 4 - 1) * 4;
        const float4 xnxt = *(const float4*)(xrow + pf);
        const float xw[4] = {xcur.x, xcur.y, xcur.z, xcur.w};

        #pragma unroll
        for (int k = 0; k < 4; ++k) {
            // ---- layer 0: systolic over rot = broadcast of h0(t-1) ----
            float a = fmaf(xw[k], wih0i, b0c), bq = 0.f, c = 0.f, d = 0.f;
            a  = fmaf(whh0r[0],  rot[0],  a);
            a  = fmaf(whh0r[1],  rot[1],  a);
            a  = fmaf(whh0r[2],  rot[2],  a);
            a  = fmaf(whh0r[3],  rot[3],  a);
            bq = fmaf(whh0r[4],  rot[4],  bq);
            bq = fmaf(whh0r[5],  rot[5],  bq);
            bq = fmaf(whh0r[6],  rot[6],  bq);
            bq = fmaf(whh0r[7],  rot[7],  bq);
            c  = fmaf(whh0r[8],  rot[8],  c);
            c  = fmaf(whh0r[9],  rot[9],  c);
            c  = fmaf(whh0r[10], rot[10], c);
            c  = fmaf(whh0r[11], rot[11], c);
            d  = fmaf(whh0r[12], rot[12], d);
            d  = fmaf(whh0r[13], rot[13], d);
            d  = fmaf(whh0r[14], rot[14], d);
            d  = fmaf(whh0r[15], rot[15], d);
            h0own = fast_tanh((a + bq) + (c + d));

            // ---- rotate h0(t): feeds layer1 now AND layer0 next step ----
            float nrot[16];
            ROT15(nrot, h0own);

            // ---- layer 1: systolic Wih1.h0(t) + plain Whh1.h1(t-1) ----
            float e = b1c, f = 0.f, g = 0.f, h = 0.f;
            e = fmaf(wih1r[0],  nrot[0],  e);
            e = fmaf(wih1r[1],  nrot[1],  e);
            e = fmaf(wih1r[2],  nrot[2],  e);
            e = fmaf(wih1r[3],  nrot[3],  e);
            e = fmaf(wih1r[4],  nrot[4],  e);
            e = fmaf(wih1r[5],  nrot[5],  e);
            e = fmaf(wih1r[6],  nrot[6],  e);
            e = fmaf(wih1r[7],  nrot[7],  e);
            f = fmaf(wih1r[8],  nrot[8],  f);
            f = fmaf(wih1r[9],  nrot[9],  f);
            f = fmaf(wih1r[10], nrot[10], f);
            f = fmaf(wih1r[11], nrot[11], f);
            f = fmaf(wih1r[12], nrot[12], f);
            f = fmaf(wih1r[13], nrot[13], f);
            f = fmaf(wih1r[14], nrot[14], f);
            f = fmaf(wih1r[15], nrot[15], f);
            g = fmaf(whh1[0], m0.x, g);
            g = fmaf(whh1[1], m0.y, g);
            g = fmaf(whh1[2], m0.z, g);
            g = fmaf(whh1[3], m0.w, g);
            g = fmaf(whh1[4], m1.x, g);
            h = fmaf(whh1[5], m1.y, h);
            h = fmaf(whh1[6], m1.z, h);
            h = fmaf(whh1[7], m1.w, h);
            h = fmaf(whh1[8], m2.x, h);
            h = fmaf(whh1[9], m2.y, h);
            h1own = fast_tanh((e + f) + (g + h));

            // ---- h1 broadcast via LDS; consumed NEXT step (~70 insts away) --
            hbuf[16 + lane] = h1own;
            __builtin_amdgcn_wave_barrier();
            m0 = *(const float4*)&hbuf[16];
            m1 = *(const float4*)&hbuf[20];
            m2 = *(const float2*)&hbuf[24];

            // ---- out(t) = Wout.h1(t) + bo : ror-butterfly all-reduce ----
            float p = woutu * h1own;
            p += rorf<0x128>(p);
            p += rorf<0x124>(p);
            p += rorf<0x122>(p);
            p += rorf<0x121>(p);
            const float o = p + bo;
            if      (k == 0) st0 = o;
            else if (k == 1) st1 = o;
            else if (k == 2) st2 = o;
            else             st3 = o;

            // commit rotations (SSA-renamed by full unroll; no real movs)
            #pragma unroll
            for (int r2 = 0; r2 < 16; ++r2) rot[r2] = nrot[r2];
        }

        if (lane == 0) {
            *(float4*)(orow + b * 4) = make_float4(st0, st1, st2, st3);
        }
        xcur = xnxt;
    }

    // final hidden state: [2, B, H] appended after B*T outputs
    if (act) {
        out[(size_t)BB * TT + (size_t)row * HID + lane]                    = h0own;
        out[(size_t)BB * TT + (size_t)BB * HID + (size_t)row * HID + lane] = h1own;
    }
}

extern "C" void kernel_launch(void* const* d_in, const int* in_sizes, int n_in,
                              void* d_out, int out_size, void* d_ws, size_t ws_size,
                              hipStream_t stream) {
    const float* x    = (const float*)d_in[0];
    const float* hs   = (const float*)d_in[1];
    const float* Wih0 = (const float*)d_in[2];
    const float* Whh0 = (const float*)d_in[3];
    const float* bih0 = (const float*)d_in[4];
    const float* bhh0 = (const float*)d_in[5];
    const float* Wih1 = (const float*)d_in[6];
    const float* Whh1 = (const float*)d_in[7];
    const float* bih1 = (const float*)d_in[8];
    const float* bhh1 = (const float*)d_in[9];
    const float* Wout = (const float*)d_in[10];
    const float* bout = (const float*)d_in[11];
    float* out = (float*)d_out;

    dim3 grid(BB / 4), block(64);
    hipLaunchKernelGGL(rnn_kernel, grid, block, 0, stream,
        x, hs, Wih0, Whh0, bih0, bhh0, Wih1, Whh1, bih1, bhh1, Wout, bout, out);
}